// Round 1
// baseline (22591.835 us; speedup 1.0000x reference)
//
#include <hip/hip_runtime.h>
#include <hip/hip_bf16.h>

// ScannedRNN: 2-cell LayerNorm-GRU scan. T=512, B=128, H=512.
// Persistent cooperative-style kernel with custom device-scope barriers.
// Per step: G1 (cell0 GEMM, A=[ins[t]|h] K=1024) -> bar -> EW0 (LN+gates) ->
//           bar -> G2 (cell1 GEMM, A=h1 K=512)   -> bar -> EW1 (+ys)     -> bar
// Weights bf16-packed once per launch, LDS-resident per-WG for the whole scan.

#define TT 512
#define BB 128
#define HH 512
#define NWG 64
#define CPW 32            // weight columns per WG per cell
#define CNT_STRIDE 16     // one counter per 64B line
#define FLAG_WORD 32768   // resets-dtype flag location (word index in cnt region)

typedef __attribute__((ext_vector_type(8))) short short8;
typedef __attribute__((ext_vector_type(4))) float f32x4;

__device__ __forceinline__ short f2bf(float f) {
  // round-to-nearest-even f32 -> bf16
  unsigned u = __float_as_uint(f);
  unsigned r = (u + 0x7fffu + ((u >> 16) & 1u)) >> 16;
  return (short)r;
}
__device__ __forceinline__ float sigf(float x) { return 1.f / (1.f + __expf(-x)); }

__device__ __forceinline__ void gridbar(unsigned* cnt, int idx) {
  __syncthreads();
  if (threadIdx.x == 0) {
    __threadfence();
    __hip_atomic_fetch_add(&cnt[idx * CNT_STRIDE], 1u, __ATOMIC_ACQ_REL, __HIP_MEMORY_SCOPE_AGENT);
    while (__hip_atomic_load(&cnt[idx * CNT_STRIDE], __ATOMIC_ACQUIRE, __HIP_MEMORY_SCOPE_AGENT)
           < (unsigned)NWG) {
      __builtin_amdgcn_s_sleep(2);
    }
    __threadfence();
  }
  __syncthreads();
}

// ---------------- pack: weights f32 -> bf16, combined/augmented layouts ----------------
// W0p [2048 cols][1024 k]  cols: 0..511 r, 512..1023 z, 1024..1535 xn(ins-only), 1536..2047 hn(h-only)
//   k<512 = ins-half (Wi[0]), k>=512 = h-half (Wh_rz[0]/Wh_n[0]); zero blocks for xn/hn.
// W1p [2048 cols][512 k]   cols: r=(Wi1+Whrz1), z=(Wi1+Whrz1), xn=Wi1_n, hn=Whn1
__global__ void pack_kernel(const float* __restrict__ Wi, const float* __restrict__ Wh_rz,
                            const float* __restrict__ Wh_n, const float* __restrict__ h0,
                            const void* __restrict__ resets,
                            short* __restrict__ W0p, short* __restrict__ W1p,
                            short* __restrict__ h2bf, unsigned* __restrict__ cnt) {
  int gid = blockIdx.x * 256 + threadIdx.x;
  if (gid == 0) {
    // detect resets dtype: int32 little-endian (bytes i%4!=0 all zero) vs bool (1B)
    const unsigned char* rb = (const unsigned char*)resets;
    unsigned intmode = 1u;
    for (int i = 1; i < 4096; ++i) {
      if ((i & 3) && rb[i]) { intmode = 0u; break; }
    }
    cnt[FLAG_WORD] = intmode;
  }
  const int n0 = 2048 * 128;   // W0p items (col, k8)
  const int n1 = 2048 * 64;    // W1p items
  const int n2 = (BB * HH) / 8;
  if (gid < n0) {
    int col = gid & 2047, kb = (gid >> 11) * 8;
    int reg = col >> 9, j = col & 511;
    short8 o;
#pragma unroll
    for (int i = 0; i < 8; ++i) {
      int k = kb + i; float v;
      if (reg == 0)      v = (k < 512) ? Wi[(size_t)k * 1536 + j]        : Wh_rz[(size_t)(k - 512) * 1024 + j];
      else if (reg == 1) v = (k < 512) ? Wi[(size_t)k * 1536 + 512 + j]  : Wh_rz[(size_t)(k - 512) * 1024 + 512 + j];
      else if (reg == 2) v = (k < 512) ? Wi[(size_t)k * 1536 + 1024 + j] : 0.f;
      else               v = (k < 512) ? 0.f                             : Wh_n[(size_t)(k - 512) * 512 + j];
      o[i] = f2bf(v);
    }
    *(short8*)&W0p[(size_t)col * 1024 + kb] = o;
  } else if (gid < n0 + n1) {
    int g = gid - n0;
    int col = g & 2047, kb = (g >> 11) * 8;
    int reg = col >> 9, j = col & 511;
    const float* Wi1  = Wi + (size_t)512 * 1536;
    const float* Wrz1 = Wh_rz + (size_t)512 * 1024;
    const float* Wn1  = Wh_n + (size_t)512 * 512;
    short8 o;
#pragma unroll
    for (int i = 0; i < 8; ++i) {
      int k = kb + i; float v;
      if (reg == 0)      v = Wi1[(size_t)k * 1536 + j] + Wrz1[(size_t)k * 1024 + j];
      else if (reg == 1) v = Wi1[(size_t)k * 1536 + 512 + j] + Wrz1[(size_t)k * 1024 + 512 + j];
      else if (reg == 2) v = Wi1[(size_t)k * 1536 + 1024 + j];
      else               v = Wn1[(size_t)k * 512 + j];
      o[i] = f2bf(v);
    }
    *(short8*)&W1p[(size_t)col * 512 + kb] = o;
  } else if (gid < n0 + n1 + n2) {
    int g = gid - n0 - n1;
    short8 o;
#pragma unroll
    for (int i = 0; i < 8; ++i) o[i] = f2bf(h0[(size_t)g * 8 + i]);
    *(short8*)&h2bf[(size_t)g * 8] = o;
  }
}

// ---------------- persistent scan kernel ----------------
__global__ __launch_bounds__(256, 1) void rnn_scan(
    const float* __restrict__ ins, const void* __restrict__ resets,
    const float* __restrict__ h0, const float* __restrict__ bi,
    const float* __restrict__ bh_n, const float* __restrict__ ln_s,
    const float* __restrict__ ln_b,
    const short* __restrict__ W0p, const short* __restrict__ W1p,
    short* __restrict__ h1bf, short* __restrict__ h2bf,
    float* __restrict__ pre0, float* __restrict__ pre1,
    unsigned* __restrict__ cnt, float* __restrict__ out) {
  __shared__ short ldsW0[CPW * 1024];  // 64KB, [col][k] swizzled
  __shared__ short ldsW1[CPW * 512];   // 32KB
  __shared__ float h1loc[2][HH];       // this WG's 2 batch rows, f32 state
  __shared__ float h2loc[2][HH];
  __shared__ float red[4][4];

  const int tid = threadIdx.x;
  const int wg  = blockIdx.x;
  const int wv  = tid >> 6;     // wave 0..3
  const int l   = tid & 63;
  const int c16 = l & 15;       // MFMA: A-row / B-col / C-col lane index
  const int kc  = l >> 4;       // MFMA: k-chunk (A/B), row-quad (C)
  const int rmode = (int)cnt[FLAG_WORD];
  const unsigned char* r8 = (const unsigned char*)resets;
  const int* r32 = (const int*)resets;
  float* ys = out + BB * HH;

  // load this WG's weight slices into LDS (T2 xor-swizzle on 16B granules)
  for (int i = tid; i < CPW * 1024 / 8; i += 256) {
    int s = i * 8; int c = s >> 10; int sw = s ^ ((c & 7) << 3);
    *(short8*)&ldsW0[sw] = *(const short8*)&W0p[(size_t)(wg * CPW + c) * 1024 + (s & 1023)];
  }
  for (int i = tid; i < CPW * 512 / 8; i += 256) {
    int s = i * 8; int c = s >> 9; int sw = s ^ ((c & 7) << 3);
    *(short8*)&ldsW1[sw] = *(const short8*)&W1p[(size_t)(wg * CPW + c) * 512 + (s & 511)];
  }
  for (int i = tid; i < 2 * HH; i += 256) {
    int rl = i >> 9, j = i & 511;
    h2loc[rl][j] = h0[(size_t)(wg * 2 + rl) * HH + j];
  }
  __syncthreads();

  for (int t = 0; t < TT; ++t) {
    // ---- G1: pre0[128][2048] = [ins[t] | h_masked] @ W0p  (K=1024, bf16 MFMA) ----
    {
      const float* insT = ins + (size_t)t * BB * HH;
      const int mt0 = wv * 2, mt1 = wv * 2 + 1;
      const int ar0 = mt0 * 16 + c16, ar1 = mt1 * 16 + c16;
      const bool rs0 = rmode ? (r32[t * BB + ar0] != 0) : (r8[t * BB + ar0] != 0);
      const bool rs1 = rmode ? (r32[t * BB + ar1] != 0) : (r8[t * BB + ar1] != 0);
      f32x4 a00 = {0,0,0,0}, a01 = {0,0,0,0}, a10 = {0,0,0,0}, a11 = {0,0,0,0};
      const int kof = kc * 8;
#pragma unroll 4
      for (int kt = 0; kt < 32; ++kt) {
        int k = kt * 32 + kof;
        short8 va = {}, vb = {};
        if (k < 512) {  // ins half: f32 load + cvt
          const float* p0 = insT + (size_t)ar0 * HH + k;
          const float* p1 = insT + (size_t)ar1 * HH + k;
          float4 u0 = *(const float4*)p0, u1 = *(const float4*)(p0 + 4);
          float4 w0 = *(const float4*)p1, w1 = *(const float4*)(p1 + 4);
          va[0] = f2bf(u0.x); va[1] = f2bf(u0.y); va[2] = f2bf(u0.z); va[3] = f2bf(u0.w);
          va[4] = f2bf(u1.x); va[5] = f2bf(u1.y); va[6] = f2bf(u1.z); va[7] = f2bf(u1.w);
          vb[0] = f2bf(w0.x); vb[1] = f2bf(w0.y); vb[2] = f2bf(w0.z); vb[3] = f2bf(w0.w);
          vb[4] = f2bf(w1.x); vb[5] = f2bf(w1.y); vb[6] = f2bf(w1.z); vb[7] = f2bf(w1.w);
        } else {        // h half: bf16, reset-masked rows
          int gk = k - 512;
          if (!rs0) va = *(const short8*)&h2bf[(size_t)ar0 * HH + gk];
          if (!rs1) vb = *(const short8*)&h2bf[(size_t)ar1 * HH + gk];
        }
        int s0 = (c16 << 10) + kt * 32 + kof;        s0 ^= (c16 & 7) << 3;
        int s1 = ((16 + c16) << 10) + kt * 32 + kof; s1 ^= (c16 & 7) << 3;
        short8 b0 = *(const short8*)&ldsW0[s0];
        short8 b1 = *(const short8*)&ldsW0[s1];
        a00 = __builtin_amdgcn_mfma_f32_16x16x32_bf16(va, b0, a00, 0, 0, 0);
        a01 = __builtin_amdgcn_mfma_f32_16x16x32_bf16(va, b1, a01, 0, 0, 0);
        a10 = __builtin_amdgcn_mfma_f32_16x16x32_bf16(vb, b0, a10, 0, 0, 0);
        a11 = __builtin_amdgcn_mfma_f32_16x16x32_bf16(vb, b1, a11, 0, 0, 0);
      }
      const int cg = wg * CPW + c16;
#pragma unroll
      for (int r = 0; r < 4; ++r) {
        int row0 = mt0 * 16 + kc * 4 + r, row1 = mt1 * 16 + kc * 4 + r;
        pre0[(size_t)row0 * 2048 + cg]      = a00[r];
        pre0[(size_t)row0 * 2048 + cg + 16] = a01[r];
        pre0[(size_t)row1 * 2048 + cg]      = a10[r];
        pre0[(size_t)row1 * 2048 + cg + 16] = a11[r];
      }
    }
    gridbar(cnt, t * 4 + 0);

    // ---- EW0: LN + gates for cell0, rows (2*wg, 2*wg+1) -> h1 ----
    {
      const int rloc = tid >> 7;
      const int row = wg * 2 + rloc;
      const int jb = tid & 127;
      const float* prow = pre0 + (size_t)row * 2048;
      float pr[4], pz[4];
      float sr = 0, sr2 = 0, sz = 0, sz2 = 0;
#pragma unroll
      for (int q = 0; q < 4; ++q) {
        int j = jb + q * 128;
        float a = prow[j] + bi[j];
        float b = prow[512 + j] + bi[512 + j];
        pr[q] = a; pz[q] = b;
        sr += a; sr2 += a * a; sz += b; sz2 += b * b;
      }
#pragma unroll
      for (int off = 32; off >= 1; off >>= 1) {
        sr += __shfl_xor(sr, off); sr2 += __shfl_xor(sr2, off);
        sz += __shfl_xor(sz, off); sz2 += __shfl_xor(sz2, off);
      }
      if (l == 0) { red[wv][0] = sr; red[wv][1] = sr2; red[wv][2] = sz; red[wv][3] = sz2; }
      __syncthreads();
      int w0 = rloc * 2;
      float Sr = red[w0][0] + red[w0 + 1][0], Sr2 = red[w0][1] + red[w0 + 1][1];
      float Sz = red[w0][2] + red[w0 + 1][2], Sz2 = red[w0][3] + red[w0 + 1][3];
      float mr = Sr * (1.f / 512.f), vr = Sr2 * (1.f / 512.f) - mr * mr;
      float mz = Sz * (1.f / 512.f), vz = Sz2 * (1.f / 512.f) - mz * mz;
      float ir = rsqrtf(vr + 1e-6f), iz = rsqrtf(vz + 1e-6f);
      const bool rst = rmode ? (r32[t * BB + row] != 0) : (r8[t * BB + row] != 0);
#pragma unroll
      for (int q = 0; q < 4; ++q) {
        int j = jb + q * 128;
        float rg = sigf((pr[q] - mr) * ir * ln_s[j] + ln_b[j]);
        float zg = sigf((pz[q] - mz) * iz * ln_s[512 + j] + ln_b[512 + j]);
        float xn = prow[1024 + j] + bi[1024 + j];
        float hn = prow[1536 + j] + bh_n[j];
        float nn = tanhf(xn + rg * hn);
        float hp = rst ? 0.f : h2loc[rloc][j];
        float h1 = (1.f - zg) * nn + zg * hp;
        h1loc[rloc][j] = h1;
        h1bf[(size_t)row * HH + j] = f2bf(h1);
      }
    }
    gridbar(cnt, t * 4 + 1);

    // ---- G2: pre1[128][2048] = h1 @ W1p  (K=512) ----
    {
      const int mt0 = wv * 2, mt1 = wv * 2 + 1;
      const int ar0 = mt0 * 16 + c16, ar1 = mt1 * 16 + c16;
      f32x4 a00 = {0,0,0,0}, a01 = {0,0,0,0}, a10 = {0,0,0,0}, a11 = {0,0,0,0};
      const int kof = kc * 8;
#pragma unroll 4
      for (int kt = 0; kt < 16; ++kt) {
        int k = kt * 32 + kof;
        short8 va = *(const short8*)&h1bf[(size_t)ar0 * HH + k];
        short8 vb = *(const short8*)&h1bf[(size_t)ar1 * HH + k];
        int s0 = (c16 << 9) + kt * 32 + kof;        s0 ^= (c16 & 7) << 3;
        int s1 = ((16 + c16) << 9) + kt * 32 + kof; s1 ^= (c16 & 7) << 3;
        short8 b0 = *(const short8*)&ldsW1[s0];
        short8 b1 = *(const short8*)&ldsW1[s1];
        a00 = __builtin_amdgcn_mfma_f32_16x16x32_bf16(va, b0, a00, 0, 0, 0);
        a01 = __builtin_amdgcn_mfma_f32_16x16x32_bf16(va, b1, a01, 0, 0, 0);
        a10 = __builtin_amdgcn_mfma_f32_16x16x32_bf16(vb, b0, a10, 0, 0, 0);
        a11 = __builtin_amdgcn_mfma_f32_16x16x32_bf16(vb, b1, a11, 0, 0, 0);
      }
      const int cg = wg * CPW + c16;
#pragma unroll
      for (int r = 0; r < 4; ++r) {
        int row0 = mt0 * 16 + kc * 4 + r, row1 = mt1 * 16 + kc * 4 + r;
        pre1[(size_t)row0 * 2048 + cg]      = a00[r];
        pre1[(size_t)row0 * 2048 + cg + 16] = a01[r];
        pre1[(size_t)row1 * 2048 + cg]      = a10[r];
        pre1[(size_t)row1 * 2048 + cg + 16] = a11[r];
      }
    }
    gridbar(cnt, t * 4 + 2);

    // ---- EW1: LN + gates for cell1 (hidden = h1) -> h2, ys[t] ----
    {
      const int rloc = tid >> 7;
      const int row = wg * 2 + rloc;
      const int jb = tid & 127;
      const float* prow = pre1 + (size_t)row * 2048;
      const float* bi1 = bi + 1536;
      const float* ls1 = ln_s + 1024;
      const float* lb1 = ln_b + 1024;
      const float* bh1 = bh_n + 512;
      float pr[4], pz[4];
      float sr = 0, sr2 = 0, sz = 0, sz2 = 0;
#pragma unroll
      for (int q = 0; q < 4; ++q) {
        int j = jb + q * 128;
        float a = prow[j] + bi1[j];
        float b = prow[512 + j] + bi1[512 + j];
        pr[q] = a; pz[q] = b;
        sr += a; sr2 += a * a; sz += b; sz2 += b * b;
      }
#pragma unroll
      for (int off = 32; off >= 1; off >>= 1) {
        sr += __shfl_xor(sr, off); sr2 += __shfl_xor(sr2, off);
        sz += __shfl_xor(sz, off); sz2 += __shfl_xor(sz2, off);
      }
      if (l == 0) { red[wv][0] = sr; red[wv][1] = sr2; red[wv][2] = sz; red[wv][3] = sz2; }
      __syncthreads();
      int w0 = rloc * 2;
      float Sr = red[w0][0] + red[w0 + 1][0], Sr2 = red[w0][1] + red[w0 + 1][1];
      float Sz = red[w0][2] + red[w0 + 1][2], Sz2 = red[w0][3] + red[w0 + 1][3];
      float mr = Sr * (1.f / 512.f), vr = Sr2 * (1.f / 512.f) - mr * mr;
      float mz = Sz * (1.f / 512.f), vz = Sz2 * (1.f / 512.f) - mz * mz;
      float ir = rsqrtf(vr + 1e-6f), iz = rsqrtf(vz + 1e-6f);
#pragma unroll
      for (int q = 0; q < 4; ++q) {
        int j = jb + q * 128;
        float rg = sigf((pr[q] - mr) * ir * ls1[j] + lb1[j]);
        float zg = sigf((pz[q] - mz) * iz * ls1[512 + j] + lb1[512 + j]);
        float xn = prow[1024 + j] + bi1[1024 + j];
        float hn = prow[1536 + j] + bh1[j];
        float nn = tanhf(xn + rg * hn);
        float hp = h1loc[rloc][j];
        float h2v = (1.f - zg) * nn + zg * hp;
        h2loc[rloc][j] = h2v;
        h2bf[(size_t)row * HH + j] = f2bf(h2v);
        ys[(size_t)t * BB * HH + (size_t)row * HH + j] = h2v;
        if (t == TT - 1) out[(size_t)row * HH + j] = h2v;
      }
    }
    gridbar(cnt, t * 4 + 3);
  }
}

extern "C" void kernel_launch(void* const* d_in, const int* in_sizes, int n_in,
                              void* d_out, int out_size, void* d_ws, size_t ws_size,
                              hipStream_t stream) {
  const float* ins   = (const float*)d_in[0];
  const void*  rstp  = d_in[1];
  const float* h0    = (const float*)d_in[2];
  const float* Wi    = (const float*)d_in[3];
  const float* bi    = (const float*)d_in[4];
  const float* Wh_rz = (const float*)d_in[5];
  const float* Wh_n  = (const float*)d_in[6];
  const float* bh_n  = (const float*)d_in[7];
  const float* ln_s  = (const float*)d_in[8];
  const float* ln_b  = (const float*)d_in[9];
  (void)in_sizes; (void)n_in; (void)out_size; (void)ws_size;

  char* ws = (char*)d_ws;
  unsigned* cnt = (unsigned*)ws;                  // 2048 barrier counters (64B apart) + flag
  size_t off = 144 * 1024;
  short* W0p  = (short*)(ws + off); off += (size_t)2048 * 1024 * 2;
  short* W1p  = (short*)(ws + off); off += (size_t)2048 * 512 * 2;
  short* h1bf = (short*)(ws + off); off += (size_t)BB * HH * 2;
  short* h2bf = (short*)(ws + off); off += (size_t)BB * HH * 2;
  float* pre0 = (float*)(ws + off); off += (size_t)BB * 2048 * 4;
  float* pre1 = (float*)(ws + off); off += (size_t)BB * 2048 * 4;
  // total ws use ~8.5 MB

  hipMemsetAsync(cnt, 0, (FLAG_WORD + 1) * sizeof(unsigned), stream);
  pack_kernel<<<1568, 256, 0, stream>>>(Wi, Wh_rz, Wh_n, h0, rstp, W0p, W1p, h2bf, cnt);
  rnn_scan<<<NWG, 256, 0, stream>>>(ins, rstp, h0, bi, bh_n, ln_s, ln_b,
                                    W0p, W1p, h1bf, h2bf, pre0, pre1, cnt, (float*)d_out);
}

// Round 2
// 18207.881 us; speedup vs baseline: 1.2408x; 1.2408x over previous
//
#include <hip/hip_runtime.h>
#include <hip/hip_bf16.h>

// ScannedRNN: 2-cell LayerNorm-GRU scan. T=512, B=128, H=512.
// Persistent kernel, 64 WGs, col-split GEMMs + row-split elementwise, with
// fence-free grid barriers: ALL cross-WG data uses agent-scope RELAXED
// atomics (sc1 -> bypass non-coherent L2, served by Infinity Cache), so the
// barrier needs no buffer_wbl2/buffer_inv L2 flushes.
// Per step: G1 (K=1024, A=[ins[t]|h]) -> bar -> EW0 -> bar -> G2 (K=512) ->
//           bar -> EW1 (+ys) -> bar.

#define TT 512
#define BB 128
#define HH 512
#define NWG 64
#define CPW 32            // weight columns per WG per cell
#define CNT_STRIDE 16     // one counter per 64B line
#define FLAG_WORD 32768   // resets-dtype flag (word index in cnt region)

typedef __attribute__((ext_vector_type(8))) short short8;
typedef __attribute__((ext_vector_type(4))) float f32x4;
typedef unsigned long long u64;

__device__ __forceinline__ short f2bf(float f) {
  unsigned u = __float_as_uint(f);
  unsigned r = (u + 0x7fffu + ((u >> 16) & 1u)) >> 16;
  return (short)r;
}
__device__ __forceinline__ float sigf(float x) { return 1.f / (1.f + __expf(-x)); }

// ---- MALL (Infinity-Cache) direct access: agent-scope relaxed => sc1, L2-bypass ----
__device__ __forceinline__ void stf(float* p, float v) {
  __hip_atomic_store(p, v, __ATOMIC_RELAXED, __HIP_MEMORY_SCOPE_AGENT);
}
__device__ __forceinline__ void st64(void* p, u64 v) {
  __hip_atomic_store((u64*)p, v, __ATOMIC_RELAXED, __HIP_MEMORY_SCOPE_AGENT);
}
__device__ __forceinline__ u64 ld64(const void* p) {
  return __hip_atomic_load((const u64*)p, __ATOMIC_RELAXED, __HIP_MEMORY_SCOPE_AGENT);
}
__device__ __forceinline__ short8 ldbf8(const short* p) {
  u64 a = ld64(p), b = ld64(p + 4);
  short8 r;
  r[0] = (short)a; r[1] = (short)(a >> 16); r[2] = (short)(a >> 32); r[3] = (short)(a >> 48);
  r[4] = (short)b; r[5] = (short)(b >> 16); r[6] = (short)(b >> 32); r[7] = (short)(b >> 48);
  return r;
}
__device__ __forceinline__ void ld2f(const float* p, float& x, float& y) {
  u64 v = ld64(p);
  x = __uint_as_float((unsigned)v);
  y = __uint_as_float((unsigned)(v >> 32));
}
__device__ __forceinline__ u64 pk4(float a, float b, float c, float d) {
  return (u64)(unsigned short)f2bf(a) | ((u64)(unsigned short)f2bf(b) << 16)
       | ((u64)(unsigned short)f2bf(c) << 32) | ((u64)(unsigned short)f2bf(d) << 48);
}

// fence-free grid barrier: __syncthreads drains vmcnt for every thread's sc1
// stores; counter ops are relaxed agent atomics (MALL-coherent, no L2 flush).
__device__ __forceinline__ void gridbar(unsigned* cnt, int idx) {
  __syncthreads();
  if (threadIdx.x == 0) {
    __hip_atomic_fetch_add(&cnt[idx * CNT_STRIDE], 1u, __ATOMIC_RELAXED, __HIP_MEMORY_SCOPE_AGENT);
    while (__hip_atomic_load(&cnt[idx * CNT_STRIDE], __ATOMIC_RELAXED, __HIP_MEMORY_SCOPE_AGENT)
           < (unsigned)NWG) {
      __builtin_amdgcn_s_sleep(1);
    }
  }
  __syncthreads();
}

// ---------------- pack: weights f32 -> bf16, combined/augmented layouts ----------------
__global__ void pack_kernel(const float* __restrict__ Wi, const float* __restrict__ Wh_rz,
                            const float* __restrict__ Wh_n, const float* __restrict__ h0,
                            const void* __restrict__ resets,
                            short* __restrict__ W0p, short* __restrict__ W1p,
                            short* __restrict__ h2bf, unsigned* __restrict__ cnt) {
  int gid = blockIdx.x * 256 + threadIdx.x;
  if (gid == 0) {
    const unsigned char* rb = (const unsigned char*)resets;
    unsigned intmode = 1u;
    for (int i = 1; i < 4096; ++i) {
      if ((i & 3) && rb[i]) { intmode = 0u; break; }
    }
    cnt[FLAG_WORD] = intmode;
  }
  const int n0 = 2048 * 128;
  const int n1 = 2048 * 64;
  const int n2 = (BB * HH) / 8;
  if (gid < n0) {
    int col = gid & 2047, kb = (gid >> 11) * 8;
    int reg = col >> 9, j = col & 511;
    short8 o;
#pragma unroll
    for (int i = 0; i < 8; ++i) {
      int k = kb + i; float v;
      if (reg == 0)      v = (k < 512) ? Wi[(size_t)k * 1536 + j]        : Wh_rz[(size_t)(k - 512) * 1024 + j];
      else if (reg == 1) v = (k < 512) ? Wi[(size_t)k * 1536 + 512 + j]  : Wh_rz[(size_t)(k - 512) * 1024 + 512 + j];
      else if (reg == 2) v = (k < 512) ? Wi[(size_t)k * 1536 + 1024 + j] : 0.f;
      else               v = (k < 512) ? 0.f                             : Wh_n[(size_t)(k - 512) * 512 + j];
      o[i] = f2bf(v);
    }
    *(short8*)&W0p[(size_t)col * 1024 + kb] = o;
  } else if (gid < n0 + n1) {
    int g = gid - n0;
    int col = g & 2047, kb = (g >> 11) * 8;
    int reg = col >> 9, j = col & 511;
    const float* Wi1  = Wi + (size_t)512 * 1536;
    const float* Wrz1 = Wh_rz + (size_t)512 * 1024;
    const float* Wn1  = Wh_n + (size_t)512 * 512;
    short8 o;
#pragma unroll
    for (int i = 0; i < 8; ++i) {
      int k = kb + i; float v;
      if (reg == 0)      v = Wi1[(size_t)k * 1536 + j] + Wrz1[(size_t)k * 1024 + j];
      else if (reg == 1) v = Wi1[(size_t)k * 1536 + 512 + j] + Wrz1[(size_t)k * 1024 + 512 + j];
      else if (reg == 2) v = Wi1[(size_t)k * 1536 + 1024 + j];
      else               v = Wn1[(size_t)k * 512 + j];
      o[i] = f2bf(v);
    }
    *(short8*)&W1p[(size_t)col * 512 + kb] = o;
  } else if (gid < n0 + n1 + n2) {
    int g = gid - n0 - n1;
    short8 o;
#pragma unroll
    for (int i = 0; i < 8; ++i) o[i] = f2bf(h0[(size_t)g * 8 + i]);
    *(short8*)&h2bf[(size_t)g * 8] = o;
  }
}

// ---------------- persistent scan kernel ----------------
__global__ __launch_bounds__(256, 1) void rnn_scan(
    const float* __restrict__ ins, const void* __restrict__ resets,
    const float* __restrict__ h0, const float* __restrict__ bi,
    const float* __restrict__ bh_n, const float* __restrict__ ln_s,
    const float* __restrict__ ln_b,
    const short* __restrict__ W0p, const short* __restrict__ W1p,
    short* __restrict__ h1bf, short* __restrict__ h2bf,
    float* __restrict__ pre0, float* __restrict__ pre1,
    unsigned* __restrict__ cnt, float* __restrict__ out) {
  __shared__ short ldsW0[CPW * 1024];  // 64KB, [col][k] swizzled
  __shared__ short ldsW1[CPW * 512];   // 32KB
  __shared__ float h1loc[2][HH];       // this WG's 2 batch rows, f32 state
  __shared__ float h2loc[2][HH];
  __shared__ float red[4][4];

  const int tid = threadIdx.x;
  const int wg  = blockIdx.x;
  const int wv  = tid >> 6;
  const int l   = tid & 63;
  const int c16 = l & 15;
  const int kc  = l >> 4;
  const int rmode = (int)cnt[FLAG_WORD];
  const unsigned char* r8 = (const unsigned char*)resets;
  const int* r32 = (const int*)resets;
  float* ys = out + BB * HH;

  for (int i = tid; i < CPW * 1024 / 8; i += 256) {
    int s = i * 8; int c = s >> 10; int sw = s ^ ((c & 7) << 3);
    *(short8*)&ldsW0[sw] = *(const short8*)&W0p[(size_t)(wg * CPW + c) * 1024 + (s & 1023)];
  }
  for (int i = tid; i < CPW * 512 / 8; i += 256) {
    int s = i * 8; int c = s >> 9; int sw = s ^ ((c & 7) << 3);
    *(short8*)&ldsW1[sw] = *(const short8*)&W1p[(size_t)(wg * CPW + c) * 512 + (s & 511)];
  }
  for (int i = tid; i < 2 * HH; i += 256) {
    int rl = i >> 9, j = i & 511;
    h2loc[rl][j] = h0[(size_t)(wg * 2 + rl) * HH + j];
  }
  __syncthreads();

  for (int t = 0; t < TT; ++t) {
    // ---- G1: pre0[128][2048] = [ins[t] | h_masked] @ W0p  (K=1024) ----
    {
      const float* insT = ins + (size_t)t * BB * HH;
      const int mt0 = wv * 2, mt1 = wv * 2 + 1;
      const int ar0 = mt0 * 16 + c16, ar1 = mt1 * 16 + c16;
      const bool rs0 = rmode ? (r32[t * BB + ar0] != 0) : (r8[t * BB + ar0] != 0);
      const bool rs1 = rmode ? (r32[t * BB + ar1] != 0) : (r8[t * BB + ar1] != 0);
      f32x4 a00 = {0,0,0,0}, a01 = {0,0,0,0}, a10 = {0,0,0,0}, a11 = {0,0,0,0};
      const int kof = kc * 8;
#pragma unroll 4
      for (int kt = 0; kt < 32; ++kt) {
        int k = kt * 32 + kof;
        short8 va = {}, vb = {};
        if (k < 512) {  // ins half: f32 cached loads + cvt
          const float* p0 = insT + (size_t)ar0 * HH + k;
          const float* p1 = insT + (size_t)ar1 * HH + k;
          float4 u0 = *(const float4*)p0, u1 = *(const float4*)(p0 + 4);
          float4 w0 = *(const float4*)p1, w1 = *(const float4*)(p1 + 4);
          va[0] = f2bf(u0.x); va[1] = f2bf(u0.y); va[2] = f2bf(u0.z); va[3] = f2bf(u0.w);
          va[4] = f2bf(u1.x); va[5] = f2bf(u1.y); va[6] = f2bf(u1.z); va[7] = f2bf(u1.w);
          vb[0] = f2bf(w0.x); vb[1] = f2bf(w0.y); vb[2] = f2bf(w0.z); vb[3] = f2bf(w0.w);
          vb[4] = f2bf(w1.x); vb[5] = f2bf(w1.y); vb[6] = f2bf(w1.z); vb[7] = f2bf(w1.w);
        } else {        // h half: bf16 via MALL, reset-masked
          int gk = k - 512;
          if (!rs0) va = ldbf8(&h2bf[(size_t)ar0 * HH + gk]);
          if (!rs1) vb = ldbf8(&h2bf[(size_t)ar1 * HH + gk]);
        }
        int s0 = (c16 << 10) + kt * 32 + kof;        s0 ^= (c16 & 7) << 3;
        int s1 = ((16 + c16) << 10) + kt * 32 + kof; s1 ^= (c16 & 7) << 3;
        short8 b0 = *(const short8*)&ldsW0[s0];
        short8 b1 = *(const short8*)&ldsW0[s1];
        a00 = __builtin_amdgcn_mfma_f32_16x16x32_bf16(va, b0, a00, 0, 0, 0);
        a01 = __builtin_amdgcn_mfma_f32_16x16x32_bf16(va, b1, a01, 0, 0, 0);
        a10 = __builtin_amdgcn_mfma_f32_16x16x32_bf16(vb, b0, a10, 0, 0, 0);
        a11 = __builtin_amdgcn_mfma_f32_16x16x32_bf16(vb, b1, a11, 0, 0, 0);
      }
      const int cg = wg * CPW + c16;
#pragma unroll
      for (int r = 0; r < 4; ++r) {
        int row0 = mt0 * 16 + kc * 4 + r, row1 = mt1 * 16 + kc * 4 + r;
        stf(&pre0[(size_t)row0 * 2048 + cg],      a00[r]);
        stf(&pre0[(size_t)row0 * 2048 + cg + 16], a01[r]);
        stf(&pre0[(size_t)row1 * 2048 + cg],      a10[r]);
        stf(&pre0[(size_t)row1 * 2048 + cg + 16], a11[r]);
      }
    }
    gridbar(cnt, t * 4 + 0);

    // ---- EW0: LN + gates for cell0, rows (2wg, 2wg+1) -> h1 ----
    {
      const int rloc = tid >> 7;
      const int row = wg * 2 + rloc;
      const int j0 = (tid & 127) * 4;
      const float* prow = pre0 + (size_t)row * 2048;
      float pr[4], pz[4], xn[4], hn[4];
      ld2f(prow + j0, pr[0], pr[1]);          ld2f(prow + j0 + 2, pr[2], pr[3]);
      ld2f(prow + 512 + j0, pz[0], pz[1]);    ld2f(prow + 512 + j0 + 2, pz[2], pz[3]);
      ld2f(prow + 1024 + j0, xn[0], xn[1]);   ld2f(prow + 1024 + j0 + 2, xn[2], xn[3]);
      ld2f(prow + 1536 + j0, hn[0], hn[1]);   ld2f(prow + 1536 + j0 + 2, hn[2], hn[3]);
      float4 br = *(const float4*)&bi[j0];
      float4 bz = *(const float4*)&bi[512 + j0];
      float4 bn = *(const float4*)&bi[1024 + j0];
      float4 bh = *(const float4*)&bh_n[j0];
      float sr = 0, sr2 = 0, sz = 0, sz2 = 0;
#pragma unroll
      for (int q = 0; q < 4; ++q) {
        pr[q] += ((const float*)&br)[q];
        pz[q] += ((const float*)&bz)[q];
        sr += pr[q]; sr2 += pr[q] * pr[q];
        sz += pz[q]; sz2 += pz[q] * pz[q];
      }
#pragma unroll
      for (int off = 32; off >= 1; off >>= 1) {
        sr += __shfl_xor(sr, off); sr2 += __shfl_xor(sr2, off);
        sz += __shfl_xor(sz, off); sz2 += __shfl_xor(sz2, off);
      }
      if (l == 0) { red[wv][0] = sr; red[wv][1] = sr2; red[wv][2] = sz; red[wv][3] = sz2; }
      __syncthreads();
      int w0 = rloc * 2;
      float Sr = red[w0][0] + red[w0 + 1][0], Sr2 = red[w0][1] + red[w0 + 1][1];
      float Sz = red[w0][2] + red[w0 + 1][2], Sz2 = red[w0][3] + red[w0 + 1][3];
      float mr = Sr * (1.f / 512.f), vr = Sr2 * (1.f / 512.f) - mr * mr;
      float mz = Sz * (1.f / 512.f), vz = Sz2 * (1.f / 512.f) - mz * mz;
      float ir = rsqrtf(vr + 1e-6f), iz = rsqrtf(vz + 1e-6f);
      const bool rst = rmode ? (r32[t * BB + row] != 0) : (r8[t * BB + row] != 0);
      float4 lsr = *(const float4*)&ln_s[j0],        lbr = *(const float4*)&ln_b[j0];
      float4 lsz = *(const float4*)&ln_s[512 + j0],  lbz = *(const float4*)&ln_b[512 + j0];
      float4 hold = *(const float4*)&h2loc[rloc][j0];
      float4 h1q;
#pragma unroll
      for (int q = 0; q < 4; ++q) {
        float rg = sigf((pr[q] - mr) * ir * ((const float*)&lsr)[q] + ((const float*)&lbr)[q]);
        float zg = sigf((pz[q] - mz) * iz * ((const float*)&lsz)[q] + ((const float*)&lbz)[q]);
        float nn = tanhf(xn[q] + ((const float*)&bn)[q] + rg * (hn[q] + ((const float*)&bh)[q]));
        float hp = rst ? 0.f : ((const float*)&hold)[q];
        ((float*)&h1q)[q] = (1.f - zg) * nn + zg * hp;
      }
      *(float4*)&h1loc[rloc][j0] = h1q;
      st64(&h1bf[(size_t)row * HH + j0], pk4(h1q.x, h1q.y, h1q.z, h1q.w));
    }
    gridbar(cnt, t * 4 + 1);

    // ---- G2: pre1[128][2048] = h1 @ W1p  (K=512) ----
    {
      const int mt0 = wv * 2, mt1 = wv * 2 + 1;
      const int ar0 = mt0 * 16 + c16, ar1 = mt1 * 16 + c16;
      f32x4 a00 = {0,0,0,0}, a01 = {0,0,0,0}, a10 = {0,0,0,0}, a11 = {0,0,0,0};
      const int kof = kc * 8;
#pragma unroll 4
      for (int kt = 0; kt < 16; ++kt) {
        int k = kt * 32 + kof;
        short8 va = ldbf8(&h1bf[(size_t)ar0 * HH + k]);
        short8 vb = ldbf8(&h1bf[(size_t)ar1 * HH + k]);
        int s0 = (c16 << 9) + kt * 32 + kof;        s0 ^= (c16 & 7) << 3;
        int s1 = ((16 + c16) << 9) + kt * 32 + kof; s1 ^= (c16 & 7) << 3;
        short8 b0 = *(const short8*)&ldsW1[s0];
        short8 b1 = *(const short8*)&ldsW1[s1];
        a00 = __builtin_amdgcn_mfma_f32_16x16x32_bf16(va, b0, a00, 0, 0, 0);
        a01 = __builtin_amdgcn_mfma_f32_16x16x32_bf16(va, b1, a01, 0, 0, 0);
        a10 = __builtin_amdgcn_mfma_f32_16x16x32_bf16(vb, b0, a10, 0, 0, 0);
        a11 = __builtin_amdgcn_mfma_f32_16x16x32_bf16(vb, b1, a11, 0, 0, 0);
      }
      const int cg = wg * CPW + c16;
#pragma unroll
      for (int r = 0; r < 4; ++r) {
        int row0 = mt0 * 16 + kc * 4 + r, row1 = mt1 * 16 + kc * 4 + r;
        stf(&pre1[(size_t)row0 * 2048 + cg],      a00[r]);
        stf(&pre1[(size_t)row0 * 2048 + cg + 16], a01[r]);
        stf(&pre1[(size_t)row1 * 2048 + cg],      a10[r]);
        stf(&pre1[(size_t)row1 * 2048 + cg + 16], a11[r]);
      }
    }
    gridbar(cnt, t * 4 + 2);

    // ---- EW1: LN + gates for cell1 (hidden = h1) -> h2, ys[t] ----
    {
      const int rloc = tid >> 7;
      const int row = wg * 2 + rloc;
      const int j0 = (tid & 127) * 4;
      const float* prow = pre1 + (size_t)row * 2048;
      const float* bi1 = bi + 1536;
      const float* ls1 = ln_s + 1024;
      const float* lb1 = ln_b + 1024;
      const float* bh1 = bh_n + 512;
      float pr[4], pz[4], xn[4], hn[4];
      ld2f(prow + j0, pr[0], pr[1]);          ld2f(prow + j0 + 2, pr[2], pr[3]);
      ld2f(prow + 512 + j0, pz[0], pz[1]);    ld2f(prow + 512 + j0 + 2, pz[2], pz[3]);
      ld2f(prow + 1024 + j0, xn[0], xn[1]);   ld2f(prow + 1024 + j0 + 2, xn[2], xn[3]);
      ld2f(prow + 1536 + j0, hn[0], hn[1]);   ld2f(prow + 1536 + j0 + 2, hn[2], hn[3]);
      float4 br = *(const float4*)&bi1[j0];
      float4 bz = *(const float4*)&bi1[512 + j0];
      float4 bn = *(const float4*)&bi1[1024 + j0];
      float4 bh = *(const float4*)&bh1[j0];
      float sr = 0, sr2 = 0, sz = 0, sz2 = 0;
#pragma unroll
      for (int q = 0; q < 4; ++q) {
        pr[q] += ((const float*)&br)[q];
        pz[q] += ((const float*)&bz)[q];
        sr += pr[q]; sr2 += pr[q] * pr[q];
        sz += pz[q]; sz2 += pz[q] * pz[q];
      }
#pragma unroll
      for (int off = 32; off >= 1; off >>= 1) {
        sr += __shfl_xor(sr, off); sr2 += __shfl_xor(sr2, off);
        sz += __shfl_xor(sz, off); sz2 += __shfl_xor(sz2, off);
      }
      if (l == 0) { red[wv][0] = sr; red[wv][1] = sr2; red[wv][2] = sz; red[wv][3] = sz2; }
      __syncthreads();
      int w0 = rloc * 2;
      float Sr = red[w0][0] + red[w0 + 1][0], Sr2 = red[w0][1] + red[w0 + 1][1];
      float Sz = red[w0][2] + red[w0 + 1][2], Sz2 = red[w0][3] + red[w0 + 1][3];
      float mr = Sr * (1.f / 512.f), vr = Sr2 * (1.f / 512.f) - mr * mr;
      float mz = Sz * (1.f / 512.f), vz = Sz2 * (1.f / 512.f) - mz * mz;
      float ir = rsqrtf(vr + 1e-6f), iz = rsqrtf(vz + 1e-6f);
      float4 lsr = *(const float4*)&ls1[j0],        lbr = *(const float4*)&lb1[j0];
      float4 lsz = *(const float4*)&ls1[512 + j0],  lbz = *(const float4*)&lb1[512 + j0];
      float4 hold = *(const float4*)&h1loc[rloc][j0];
      float4 h2q;
#pragma unroll
      for (int q = 0; q < 4; ++q) {
        float rg = sigf((pr[q] - mr) * ir * ((const float*)&lsr)[q] + ((const float*)&lbr)[q]);
        float zg = sigf((pz[q] - mz) * iz * ((const float*)&lsz)[q] + ((const float*)&lbz)[q]);
        float nn = tanhf(xn[q] + ((const float*)&bn)[q] + rg * (hn[q] + ((const float*)&bh)[q]));
        float hp = ((const float*)&hold)[q];
        ((float*)&h2q)[q] = (1.f - zg) * nn + zg * hp;
      }
      *(float4*)&h2loc[rloc][j0] = h2q;
      st64(&h2bf[(size_t)row * HH + j0], pk4(h2q.x, h2q.y, h2q.z, h2q.w));
      *(float4*)&ys[(size_t)t * BB * HH + (size_t)row * HH + j0] = h2q;
      if (t == TT - 1) *(float4*)&out[(size_t)row * HH + j0] = h2q;
    }
    gridbar(cnt, t * 4 + 3);
  }
}

extern "C" void kernel_launch(void* const* d_in, const int* in_sizes, int n_in,
                              void* d_out, int out_size, void* d_ws, size_t ws_size,
                              hipStream_t stream) {
  const float* ins   = (const float*)d_in[0];
  const void*  rstp  = d_in[1];
  const float* h0    = (const float*)d_in[2];
  const float* Wi    = (const float*)d_in[3];
  const float* bi    = (const float*)d_in[4];
  const float* Wh_rz = (const float*)d_in[5];
  const float* Wh_n  = (const float*)d_in[6];
  const float* bh_n  = (const float*)d_in[7];
  const float* ln_s  = (const float*)d_in[8];
  const float* ln_b  = (const float*)d_in[9];
  (void)in_sizes; (void)n_in; (void)out_size; (void)ws_size;

  char* ws = (char*)d_ws;
  unsigned* cnt = (unsigned*)ws;
  size_t off = 144 * 1024;
  short* W0p  = (short*)(ws + off); off += (size_t)2048 * 1024 * 2;
  short* W1p  = (short*)(ws + off); off += (size_t)2048 * 512 * 2;
  short* h1bf = (short*)(ws + off); off += (size_t)BB * HH * 2;
  short* h2bf = (short*)(ws + off); off += (size_t)BB * HH * 2;
  float* pre0 = (float*)(ws + off); off += (size_t)BB * 2048 * 4;
  float* pre1 = (float*)(ws + off); off += (size_t)BB * 2048 * 4;

  hipMemsetAsync(cnt, 0, (FLAG_WORD + 1) * sizeof(unsigned), stream);
  pack_kernel<<<1568, 256, 0, stream>>>(Wi, Wh_rz, Wh_n, h0, rstp, W0p, W1p, h2bf, cnt);
  rnn_scan<<<NWG, 256, 0, stream>>>(ins, rstp, h0, bi, bh_n, ln_s, ln_b,
                                    W0p, W1p, h1bf, h2bf, pre0, pre1, cnt, (float*)d_out);
}